// Round 9
// baseline (333.740 us; speedup 1.0000x reference)
//
#include <hip/hip_runtime.h>
#include <math.h>
#include <float.h>

#define Bd 4
#define Cd 256
#define Hd 128
#define Wd 128
#define HW (Hd*Wd)

#define PX 128   // pixels per block in fallback fused kernel
#define KC 32
#define PXM 32   // pixels per block in merged kernel
#define CSTR 264 // padded LDS row stride (bf16 elems)

typedef __attribute__((ext_vector_type(8))) short s16x8;
typedef __attribute__((ext_vector_type(4))) float f32x4;

// rne float -> bf16 hi, and bf16(residual) lo
__device__ __forceinline__ void bf16split(float v, ushort& h, ushort& lo_) {
  uint u = __builtin_bit_cast(uint, v);
  uint uh = u + 0x7FFFu + ((u >> 16) & 1u);
  ushort hh = (ushort)(uh >> 16);
  float hf = __builtin_bit_cast(float, (uint)hh << 16);
  float res = v - hf;                       // exact
  uint r = __builtin_bit_cast(uint, res);
  uint rl = r + 0x7FFFu + ((r >> 16) & 1u);
  h = hh; lo_ = (ushort)(rl >> 16);
}

// ---------------------------------------------------------------------------
// prep_w_k: pack w0,w1 ([O][C] fp32) into MFMA-A-fragment order, hi/lo bf16.
// wpk[((mat*2+part)*8 + kc)*16 + tile][lane][8]:
//   elem j = W[tile*16 + (lane&15)][kc*32 + (lane>>4)*8 + j]
// ---------------------------------------------------------------------------
__global__ __launch_bounds__(256) void prep_w_k(
    const float* __restrict__ w0, const float* __restrict__ w1,
    ushort* __restrict__ wpk) {
  const int t    = blockIdx.x * 256 + threadIdx.x;  // 0..16383
  const int lane = t & 63;
  const int tile = (t >> 6) & 15;
  const int kc   = (t >> 10) & 7;
  const int mat  = t >> 13;
  const float* wsrc = mat ? w1 : w0;
  const int o  = tile * 16 + (lane & 15);
  const int c0 = kc * 32 + (lane >> 4) * 8;
  ushort hi[8], lo[8];
#pragma unroll
  for (int j = 0; j < 8; ++j)
    bf16split(wsrc[o * Cd + c0 + j], hi[j], lo[j]);
  const size_t bh = ((((size_t)(mat * 2 + 0) * 8 + kc) * 16 + tile) * 64 + lane) * 8;
  const size_t bl = ((((size_t)(mat * 2 + 1) * 8 + kc) * 16 + tile) * 64 + lane) * 8;
#pragma unroll
  for (int j = 0; j < 8; ++j) { wpk[bh + j] = hi[j]; wpk[bl + j] = lo[j]; }
}

// ---------------------------------------------------------------------------
// transpose_x_k: x [B][C][HW] -> xT [B][HW][C] (fp32), for coalesced gathers.
// ---------------------------------------------------------------------------
__global__ __launch_bounds__(256) void transpose_x_k(
    const float* __restrict__ x, float* __restrict__ xT) {
  __shared__ float t[32][33];
  const int b   = blockIdx.z;
  const int hw0 = blockIdx.x * 32;
  const int c0  = blockIdx.y * 32;
  const int tx = threadIdx.x & 31, ty = threadIdx.x >> 5;
  const float* xb  = x  + (size_t)b * Cd * HW;
  float*       xTb = xT + (size_t)b * HW * Cd;
#pragma unroll
  for (int i = 0; i < 32; i += 8)
    t[ty + i][tx] = xb[(size_t)(c0 + ty + i) * HW + hw0 + tx];
  __syncthreads();
#pragma unroll
  for (int i = 0; i < 32; i += 8)
    xTb[(size_t)(hw0 + ty + i) * Cd + c0 + tx] = t[tx][ty + i];
}

// ---------------------------------------------------------------------------
// deform_job: one (pixel,tap) bilinear coeff job -> 4 indices + 4 weights.
// ---------------------------------------------------------------------------
__device__ __forceinline__ void deform_job(
    int j, int pbase, const float* __restrict__ offb, uint* __restrict__ dstbase) {
  const int px = j / 9, k = j - px * 9;
  const int p = pbase + px;
  const int h = p >> 7, w = p & (Wd - 1);
  const float oy = offb[(2 * k) * HW + p];
  const float ox = offb[(2 * k + 1) * HW + p];
  const float py = (float)(h + k / 3 - 1) + oy;
  const float pxx = (float)(w + k % 3 - 1) + ox;
  const float y0f = floorf(py), x0f = floorf(pxx);
  const float wy = py - y0f, wx = pxx - x0f;
  const int y0 = (int)y0f, x0 = (int)x0f;
  const int y1 = y0 + 1,  x1 = x0 + 1;
  const float vy0 = (y0 >= 0 && y0 < Hd) ? 1.f : 0.f;
  const float vy1 = (y1 >= 0 && y1 < Hd) ? 1.f : 0.f;
  const float vx0 = (x0 >= 0 && x0 < Wd) ? 1.f : 0.f;
  const float vx1 = (x1 >= 0 && x1 < Wd) ? 1.f : 0.f;
  const int cy0 = min(max(y0, 0), Hd-1), cy1 = min(max(y1, 0), Hd-1);
  const int cx0 = min(max(x0, 0), Wd-1), cx1 = min(max(x1, 0), Wd-1);
  uint4 iv;
  iv.x = (uint)(cy0 * Wd + cx0) * Cd;
  iv.y = (uint)(cy0 * Wd + cx1) * Cd;
  iv.z = (uint)(cy1 * Wd + cx0) * Cd;
  iv.w = (uint)(cy1 * Wd + cx1) * Cd;
  float4 cv;
  cv.x = (1.f-wy)*(1.f-wx) * vy0*vx0;
  cv.y = (1.f-wy)*wx       * vy0*vx1;
  cv.z = wy*(1.f-wx)       * vy1*vx0;
  cv.w = wy*wx             * vy1*vx1;
  uint* d = dstbase + (size_t)(px * 9 + k) * 8;
  *(uint4*)d = iv;
  *(float4*)(d + 4) = cv;
}

// ---------------------------------------------------------------------------
// merged_k (R8): deform gather+max fused with split-bf16 MFMA GEMMs.
// R8 vs R7: x no longer staged in LDS — the K-loop loads x B-fragments
// directly from global (lanes l,l+16,l+32,l+48 cover one row's 128 B -> full
// line coalescing, L1/L2-resident) and bf16splits in registers. LDS drops
// 76.8 -> 43 KB => 3 blocks/CU (12 waves/CU) via __launch_bounds__(256,3).
// Also removes the x half of the K-loop LDS reads (fewer bank conflicts).
// ---------------------------------------------------------------------------
__global__ __launch_bounds__(256, 3) void merged_k(
    const float* __restrict__ xT, const float* __restrict__ off,
    const ushort* __restrict__ wpk,
    const float* __restrict__ b0, const float* __restrict__ b1,
    float* __restrict__ out) {
  __shared__ ushort act[2 * PXM * CSTR];            // qh|ql = 33792 B
  __shared__ __align__(16) uint coef[4][8 * 9 * 8]; // 9216 B (tot 43 KB)

  // XCD-chunked swizzle over 2048 blocks (2048 % 8 == 0 -> bijective).
  const int bid = blockIdx.x;
  const int swz = (bid & 7) * 256 + (bid >> 3);
  const int b    = swz >> 9;            // 512 blocks per batch
  const int tile = swz & 511;

  const int tid = threadIdx.x;
  const int l   = tid & 63, wv = tid >> 6;
  const int px0   = tile * PXM;         // block's 32 pixels
  const int pbase = px0 + wv * 8;       // wave's 8 pixels

  const float* offb = off + (size_t)b * 18 * HW;

  // ---- Phase A: coeffs (72 jobs across 64 lanes)
  deform_job(l, pbase, offb, &coef[wv][0]);
  if (l < 8) deform_job(64 + l, pbase, offb, &coef[wv][0]);
  __syncthreads();

  // ---- Phase B: gather + max + bf16split -> act q rows
  {
    const float* xTb = xT + (size_t)b * HW * Cd + l * 4;
    ushort* qh_base = act + 0 * PXM * CSTR;
    ushort* ql_base = act + 1 * PXM * CSTR;
#pragma unroll 2
    for (int pi = 0; pi < 8; ++pi) {
      float m0 = -FLT_MAX, m1 = -FLT_MAX, m2 = -FLT_MAX, m3 = -FLT_MAX;
#pragma unroll
      for (int k = 0; k < 9; ++k) {
        const uint* cp = &coef[wv][(pi * 9 + k) * 8];
        const uint4  iv = *(const uint4*)cp;        // wave-uniform broadcast
        const float4 cw = *(const float4*)(cp + 4);
        const float4 v00 = *(const float4*)(xTb + iv.x);
        const float4 v01 = *(const float4*)(xTb + iv.y);
        const float4 v10 = *(const float4*)(xTb + iv.z);
        const float4 v11 = *(const float4*)(xTb + iv.w);
        m0 = fmaxf(m0, fmaf(cw.x, v00.x, fmaf(cw.y, v01.x, fmaf(cw.z, v10.x, cw.w*v11.x))));
        m1 = fmaxf(m1, fmaf(cw.x, v00.y, fmaf(cw.y, v01.y, fmaf(cw.z, v10.y, cw.w*v11.y))));
        m2 = fmaxf(m2, fmaf(cw.x, v00.z, fmaf(cw.y, v01.z, fmaf(cw.z, v10.z, cw.w*v11.z))));
        m3 = fmaxf(m3, fmaf(cw.x, v00.w, fmaf(cw.y, v01.w, fmaf(cw.z, v10.w, cw.w*v11.w))));
      }
      ushort4 hh, ll;
      bf16split(m0, hh.x, ll.x); bf16split(m1, hh.y, ll.y);
      bf16split(m2, hh.z, ll.z); bf16split(m3, hh.w, ll.w);
      const int pl = wv * 8 + pi;                   // local pixel row 0..31
      *(ushort4*)(qh_base + pl * CSTR + l * 4) = hh;
      *(ushort4*)(ql_base + pl * CSTR + l * 4) = ll;
    }
  }
  __syncthreads();

  // ---- Phase D: K-loop (no barriers). q from LDS; x from global; W from wpk.
  const f32x4 z = {0.f, 0.f, 0.f, 0.f};
  f32x4 accQ[4][2], accK[4][2];
#pragma unroll
  for (int a = 0; a < 4; ++a)
#pragma unroll
    for (int bt = 0; bt < 2; ++bt) { accQ[a][bt] = z; accK[a][bt] = z; }

  const float* xfrag_base = xT + ((size_t)b * HW + px0 + (l & 15)) * Cd + (l >> 4) * 8;

#pragma unroll 2
  for (int kc = 0; kc < 8; ++kc) {
    // x B-frags from global: fp32 -> hi/lo bf16 in registers
    s16x8 bxh[2], bxl[2];
#pragma unroll
    for (int bt = 0; bt < 2; ++bt) {
      const float* xr = xfrag_base + (size_t)(bt * 16) * Cd + kc * 32;
      const float4 xa = *(const float4*)xr;
      const float4 xb4 = *(const float4*)(xr + 4);
      ushort h[8], lo[8];
      bf16split(xa.x,  h[0], lo[0]); bf16split(xa.y,  h[1], lo[1]);
      bf16split(xa.z,  h[2], lo[2]); bf16split(xa.w,  h[3], lo[3]);
      bf16split(xb4.x, h[4], lo[4]); bf16split(xb4.y, h[5], lo[5]);
      bf16split(xb4.z, h[6], lo[6]); bf16split(xb4.w, h[7], lo[7]);
#pragma unroll
      for (int j = 0; j < 8; ++j) { bxh[bt][j] = (short)h[j]; bxl[bt][j] = (short)lo[j]; }
    }
    // q B-frags from LDS
    s16x8 bqh[2], bql[2];
#pragma unroll
    for (int bt = 0; bt < 2; ++bt) {
      const int row  = bt * 16 + (l & 15);
      const int coff = kc * 32 + (l >> 4) * 8;
      const ushort* base = act + row * CSTR + coff;
      bqh[bt] = *(const s16x8*)(base + 0 * PXM * CSTR);
      bql[bt] = *(const s16x8*)(base + 1 * PXM * CSTR);
    }
    // A-frags per o-tile + MFMA
#pragma unroll
    for (int a = 0; a < 4; ++a) {
      const int ta = wv * 4 + a;      // 16 o-tiles / 4 waves
      const s16x8 a0h = *(const s16x8*)(wpk + (((size_t)(0 * 8 + kc) * 16 + ta) * 64 + l) * 8);
      const s16x8 a0l = *(const s16x8*)(wpk + (((size_t)(1 * 8 + kc) * 16 + ta) * 64 + l) * 8);
      const s16x8 a1h = *(const s16x8*)(wpk + (((size_t)(2 * 8 + kc) * 16 + ta) * 64 + l) * 8);
      const s16x8 a1l = *(const s16x8*)(wpk + (((size_t)(3 * 8 + kc) * 16 + ta) * 64 + l) * 8);
#pragma unroll
      for (int bt = 0; bt < 2; ++bt) {
        accQ[a][bt] = __builtin_amdgcn_mfma_f32_16x16x32_bf16(a0h, bqh[bt], accQ[a][bt], 0, 0, 0);
        accQ[a][bt] = __builtin_amdgcn_mfma_f32_16x16x32_bf16(a0h, bql[bt], accQ[a][bt], 0, 0, 0);
        accQ[a][bt] = __builtin_amdgcn_mfma_f32_16x16x32_bf16(a0l, bqh[bt], accQ[a][bt], 0, 0, 0);
        accK[a][bt] = __builtin_amdgcn_mfma_f32_16x16x32_bf16(a1h, bxh[bt], accK[a][bt], 0, 0, 0);
        accK[a][bt] = __builtin_amdgcn_mfma_f32_16x16x32_bf16(a1h, bxl[bt], accK[a][bt], 0, 0, 0);
        accK[a][bt] = __builtin_amdgcn_mfma_f32_16x16x32_bf16(a1l, bxh[bt], accK[a][bt], 0, 0, 0);
      }
    }
  }

  // ---- Phase E: epilogue.  D layout: col=l&15 -> pixel bt*16+(l&15),
  // row o = wv*64 + a*16 + (l>>4)*4 + r.
  float bq[4][4], bk[4][4];
#pragma unroll
  for (int a = 0; a < 4; ++a)
#pragma unroll
    for (int r = 0; r < 4; ++r) {
      const int o = wv * 64 + a * 16 + (l >> 4) * 4 + r;
      bq[a][r] = b0[o]; bk[a][r] = b1[o];
    }

  float st[2][5];
#pragma unroll
  for (int bt = 0; bt < 2; ++bt)
#pragma unroll
    for (int s = 0; s < 5; ++s) st[bt][s] = 0.f;
#pragma unroll
  for (int bt = 0; bt < 2; ++bt)
#pragma unroll
    for (int a = 0; a < 4; ++a)
#pragma unroll
      for (int r = 0; r < 4; ++r) {
        const float Qv = accQ[a][bt][r] + bq[a][r];
        const float Kv = accK[a][bt][r] + bk[a][r];
        st[bt][0] += Qv;
        st[bt][1] += Kv;
        st[bt][2] = fmaf(Qv, Qv, st[bt][2]);
        st[bt][3] = fmaf(Kv, Kv, st[bt][3]);
        st[bt][4] = fmaf(Qv, Kv, st[bt][4]);
      }
#pragma unroll
  for (int bt = 0; bt < 2; ++bt)
#pragma unroll
    for (int s = 0; s < 5; ++s) {
      float v = st[bt][s];
      v += __shfl_xor(v, 16, 64);
      v += __shfl_xor(v, 32, 64);      // wave's 64-out sums for pixel bt*16+(l&15)
      st[bt][s] = v;
    }

  __syncthreads();                      // act reads done; alias stats buffer
  float* sl = (float*)act;              // [4 waves][32 px][5]
  if (l < 32) {
    const int mybt = l >> 4, col = l & 15;
#pragma unroll
    for (int s = 0; s < 5; ++s)
      sl[((wv * 32) + mybt * 16 + col) * 5 + s] = st[mybt][s];
  }
  __syncthreads();
  if (tid < PXM) {
    float sQ = 0.f, sK = 0.f, sQQ = 0.f, sKK = 0.f, sQK = 0.f;
#pragma unroll
    for (int w4 = 0; w4 < 4; ++w4) {
      const float* p = sl + ((w4 * 32) + tid) * 5;
      sQ += p[0]; sK += p[1]; sQQ += p[2]; sKK += p[3]; sQK += p[4];
    }
    const float num = sQK - sQ * sK * (1.f / 256.f);
    const float dq  = sQQ - sQ * sQ * (1.f / 256.f) + 1e-5f;
    const float dk  = sKK - sK * sK * (1.f / 256.f) + 1e-5f;
    out[(size_t)b * HW + px0 + tid] = num / sqrtf(dq * dk);
  }
}

// ---------------------------------------------------------------------------
// Fallback path (R1/R2 proven), used only if ws is too small.
// ---------------------------------------------------------------------------
__global__ __launch_bounds__(256) void transpose_k(
    const float* __restrict__ w0, const float* __restrict__ w1,
    float* __restrict__ w0T, float* __restrict__ w1T) {
  __shared__ float tile[32][33];
  const float* src = blockIdx.y ? w1 : w0;
  float*       dst = blockIdx.y ? w1T : w0T;
  const int bx = blockIdx.x & 7, by = blockIdx.x >> 3;
  const int tx = threadIdx.x & 31, ty = threadIdx.x >> 5;
#pragma unroll
  for (int i = 0; i < 32; i += 8)
    tile[ty + i][tx] = src[(by*32 + ty + i)*Cd + bx*32 + tx];
  __syncthreads();
#pragma unroll
  for (int i = 0; i < 32; i += 8)
    dst[(bx*32 + ty + i)*Cd + by*32 + tx] = tile[tx][ty + i];
}

__global__ __launch_bounds__(256) void deform_max_k(
    const float* __restrict__ x, const float* __restrict__ off,
    float* __restrict__ q) {
  const int b   = blockIdx.y;
  const int c0  = blockIdx.z << 5;
  const int hw0 = (blockIdx.x << 8) + threadIdx.x;
  const int h   = hw0 >> 7;
  const int w   = hw0 & (Wd - 1);
  const float* offb = off + ((size_t)b * 18) * HW + hw0;
  int   i00[9], i01[9], i10[9], i11[9];
  float c00[9], c01[9], c10[9], c11[9];
#pragma unroll
  for (int k = 0; k < 9; ++k) {
    const int kh = k / 3 - 1, kw = k % 3 - 1;
    const float oy = offb[(size_t)(2*k)   * HW];
    const float ox = offb[(size_t)(2*k+1) * HW];
    const float py = (float)(h + kh) + oy;
    const float px = (float)(w + kw) + ox;
    const float y0f = floorf(py), x0f = floorf(px);
    const float wy = py - y0f, wx = px - x0f;
    const int y0 = (int)y0f, x0 = (int)x0f;
    const int y1 = y0 + 1,  x1 = x0 + 1;
    const float vy0 = (y0 >= 0 && y0 < Hd) ? 1.f : 0.f;
    const float vy1 = (y1 >= 0 && y1 < Hd) ? 1.f : 0.f;
    const float vx0 = (x0 >= 0 && x0 < Wd) ? 1.f : 0.f;
    const float vx1 = (x1 >= 0 && x1 < Wd) ? 1.f : 0.f;
    const int cy0 = min(max(y0, 0), Hd-1), cy1 = min(max(y1, 0), Hd-1);
    const int cx0 = min(max(x0, 0), Wd-1), cx1 = min(max(x1, 0), Wd-1);
    i00[k] = cy0 * Wd + cx0;  i01[k] = cy0 * Wd + cx1;
    i10[k] = cy1 * Wd + cx0;  i11[k] = cy1 * Wd + cx1;
    c00[k] = (1.f-wy)*(1.f-wx) * vy0*vx0;
    c01[k] = (1.f-wy)*wx       * vy0*vx1;
    c10[k] = wy*(1.f-wx)       * vy1*vx0;
    c11[k] = wy*wx             * vy1*vx1;
  }
  const float* xb = x + ((size_t)(b * Cd + c0)) * HW;
  float*       qb = q + ((size_t)(b * Cd + c0)) * HW + hw0;
#pragma unroll 4
  for (int c = 0; c < 32; ++c) {
    const float* xc = xb + (size_t)c * HW;
    float m = -3.402823466e38f;
#pragma unroll
    for (int k = 0; k < 9; ++k) {
      const float s = c00[k]*xc[i00[k]] + c01[k]*xc[i01[k]]
                    + c10[k]*xc[i10[k]] + c11[k]*xc[i11[k]];
      m = fmaxf(m, s);
    }
    qb[(size_t)c * HW] = m;
  }
}

__global__ __launch_bounds__(512) void fused_k(
    const float* __restrict__ x, const float* __restrict__ q,
    const float* __restrict__ w0T, const float* __restrict__ w1T,
    const float* __restrict__ b0, const float* __restrict__ b1,
    float* __restrict__ out) {
  __shared__ float w0s[KC * 256];
  __shared__ float w1s[KC * 256];
  __shared__ float qs [KC * PX];
  __shared__ float xs [KC * PX];
  const int b    = blockIdx.y;
  const int px0  = blockIdx.x * PX;
  const int tid  = threadIdx.x;
  const int o_t  = tid & 31;
  const int px_t = tid >> 5;
  float accQ[8][8], accK[8][8];
#pragma unroll
  for (int i = 0; i < 8; ++i) {
    const int o = (i < 4) ? (4*o_t + i) : (128 + 4*o_t + (i - 4));
    const float bqv = b0[o], bkv = b1[o];
#pragma unroll
    for (int j = 0; j < 8; ++j) { accQ[i][j] = bqv; accK[i][j] = bkv; }
  }
  const float* qb = q + ((size_t)b * Cd) * HW + px0;
  const float* xb = x + ((size_t)b * Cd) * HW + px0;
  for (int kc = 0; kc < Cd; kc += KC) {
    __syncthreads();
    {
      const float4* s0 = (const float4*)(w0T + (size_t)kc * 256);
      const float4* s1 = (const float4*)(w1T + (size_t)kc * 256);
      float4* d0 = (float4*)w0s;
      float4* d1 = (float4*)w1s;
#pragma unroll
      for (int i = 0; i < 4; ++i) {
        d0[tid*4 + i] = s0[tid*4 + i];
        d1[tid*4 + i] = s1[tid*4 + i];
      }
#pragma unroll
      for (int i = 0; i < 2; ++i) {
        const int f  = tid*2 + i;
        const int cc = f >> 5, p4 = f & 31;
        ((float4*)qs)[cc*(PX/4) + p4] =
            ((const float4*)(qb + (size_t)(kc+cc) * HW))[p4];
        ((float4*)xs)[cc*(PX/4) + p4] =
            ((const float4*)(xb + (size_t)(kc+cc) * HW))[p4];
      }
    }
    __syncthreads();
#pragma unroll 4
    for (int cc = 0; cc < KC; ++cc) {
      float a0[8], a1[8], qv[8], xv[8];
      *(float4*)&a0[0] = *(const float4*)&w0s[cc*256 + 4*o_t];
      *(float4*)&a0[4] = *(const float4*)&w0s[cc*256 + 128 + 4*o_t];
      *(float4*)&a1[0] = *(const float4*)&w1s[cc*256 + 4*o_t];
      *(float4*)&a1[4] = *(const float4*)&w1s[cc*256 + 128 + 4*o_t];
      *(float4*)&qv[0] = *(const float4*)&qs[cc*PX + 8*px_t];
      *(float4*)&qv[4] = *(const float4*)&qs[cc*PX + 8*px_t + 4];
      *(float4*)&xv[0] = *(const float4*)&xs[cc*PX + 8*px_t];
      *(float4*)&xv[4] = *(const float4*)&xs[cc*PX + 8*px_t + 4];
#pragma unroll
      for (int i = 0; i < 8; ++i)
#pragma unroll
        for (int j = 0; j < 8; ++j) {
          accQ[i][j] = fmaf(a0[i], qv[j], accQ[i][j]);
          accK[i][j] = fmaf(a1[i], xv[j], accK[i][j]);
        }
    }
  }
  float outv[8];
#pragma unroll
  for (int j = 0; j < 8; ++j) {
    float sQ = 0.f, sK = 0.f, sQQ = 0.f, sKK = 0.f, sQK = 0.f;
#pragma unroll
    for (int i = 0; i < 8; ++i) {
      const float Qv = accQ[i][j], Kv = accK[i][j];
      sQ += Qv; sK += Kv;
      sQQ = fmaf(Qv, Qv, sQQ);
      sKK = fmaf(Kv, Kv, sKK);
      sQK = fmaf(Qv, Kv, sQK);
    }
#pragma unroll
    for (int m = 1; m < 32; m <<= 1) {
      sQ  += __shfl_xor(sQ,  m, 64);
      sK  += __shfl_xor(sK,  m, 64);
      sQQ += __shfl_xor(sQQ, m, 64);
      sKK += __shfl_xor(sKK, m, 64);
      sQK += __shfl_xor(sQK, m, 64);
    }
    const float num = sQK - sQ*sK*(1.f/256.f);
    const float dq  = sQQ - sQ*sQ*(1.f/256.f) + 1e-5f;
    const float dk  = sKK - sK*sK*(1.f/256.f) + 1e-5f;
    outv[j] = num / sqrtf(dq * dk);
  }
  if (o_t == 0) {
    float* ob = out + (size_t)b * HW + px0 + px_t*8;
#pragma unroll
    for (int j = 0; j < 8; ++j) ob[j] = outv[j];
  }
}

// ---------------------------------------------------------------------------
extern "C" void kernel_launch(void* const* d_in, const int* in_sizes, int n_in,
                              void* d_out, int out_size, void* d_ws, size_t ws_size,
                              hipStream_t stream) {
  const float* x   = (const float*)d_in[0];
  const float* off = (const float*)d_in[1];
  const float* w0  = (const float*)d_in[2];
  const float* b0  = (const float*)d_in[3];
  const float* w1  = (const float*)d_in[4];
  const float* b1  = (const float*)d_in[5];
  float* out = (float*)d_out;

  const size_t tensor_elems = (size_t)Bd * Cd * HW;       // 16.78M floats
  const size_t wpk_bytes    = 4 * 65536 * sizeof(ushort); // 512 KB
  const size_t need_fast    = wpk_bytes + tensor_elems * 4;

  if (ws_size >= need_fast) {
    ushort* wpk = (ushort*)d_ws;
    float*  xT  = (float*)((char*)d_ws + wpk_bytes);      // [B][HW][C], 64 MiB
    prep_w_k     <<<64, 256, 0, stream>>>(w0, w1, wpk);
    transpose_x_k<<<dim3(HW/32, Cd/32, Bd), 256, 0, stream>>>(x, xT);
    merged_k     <<<2048, 256, 0, stream>>>(xT, off, wpk, b0, b1, out);
  } else {
    float* w0T = (float*)d_ws;
    float* w1T = w0T + 65536;
    float* qws = w1T + 65536;
    transpose_k <<<dim3(64, 2),     256, 0, stream>>>(w0, w1, w0T, w1T);
    deform_max_k<<<dim3(64, Bd, 8), 256, 0, stream>>>(x, off, qws);
    fused_k     <<<dim3(HW/PX, Bd), 512, 0, stream>>>(x, qws, w0T, w1T, b0, b1, out);
  }
}